// Round 2
// baseline (89.633 us; speedup 1.0000x reference)
//
#include <hip/hip_runtime.h>

#define HH 256
#define WW 256
#define CC 32
#define K 7
#define RAD 3
#define TS 16
#define HALO (TS + K - 1)      /* 22 */
#define NP (HALO * HALO)       /* 484 */
#define PIX_STRIDE 40          /* ushorts per pixel: 32 ch + 8 pad = 80 B */

typedef _Float16 h2 __attribute__((ext_vector_type(2)));
typedef float f2 __attribute__((ext_vector_type(2)));
typedef float f4 __attribute__((ext_vector_type(4)));
typedef unsigned int u32;
typedef u32 u2v __attribute__((ext_vector_type(2)));
typedef u32 u4v __attribute__((ext_vector_type(4)));

union U4H {
    u4v u;
    h2 h[4];
};

// __builtin_amdgcn_cvt_pkrtz returns __fp16 ext_vector(2); bit-cast to h2.
static __device__ inline h2 pkrtz(float x, float y) {
    auto t = __builtin_amdgcn_cvt_pkrtz(x, y);
    h2 r;
    __builtin_memcpy(&r, &t, sizeof(r));
    return r;
}

static __device__ inline u32 pkrtz_u(float x, float y) {
    auto t = __builtin_amdgcn_cvt_pkrtz(x, y);
    u32 r;
    __builtin_memcpy(&r, &t, sizeof(r));
    return r;
}

static __device__ inline float fdot2f(h2 a, h2 b, float c) {
#if __has_builtin(__builtin_amdgcn_fdot2)
    return __builtin_amdgcn_fdot2(a, b, c, false);
#else
    return c + (float)a[0] * (float)b[0] + (float)a[1] * (float)b[1];
#endif
}

__global__ __launch_bounds__(256) void local_attn_kernel(
    const float* __restrict__ main_in,
    const float* __restrict__ ref_in,
    const float* __restrict__ val_in,
    float* __restrict__ out)
{
    __shared__ ushort s_ref[NP * PIX_STRIDE];
    __shared__ ushort s_val[NP * PIX_STRIDE];

    const int tid = threadIdx.x;
    const int ox = blockIdx.x * TS;
    const int oy = blockIdx.y * TS;

    // ---- Stage ref & ref_value halo tiles into LDS as fp16 (zeros for OOB) ----
    // NP pixels * 8 float4-chunks per pixel per tensor.
    for (int idx = tid; idx < NP * 8; idx += 256) {
        const int pix = idx >> 3;
        const int c4 = idx & 7;                 // float4 chunk: channels 4*c4..4*c4+3
        const int hh = pix / HALO;
        const int ww = pix - hh * HALO;
        const int gh = oy + hh - RAD;
        const int gw = ox + ww - RAD;
        u2v r_out = {0u, 0u};
        u2v v_out = {0u, 0u};
        if ((unsigned)gh < (unsigned)HH && (unsigned)gw < (unsigned)WW) {
            const long goff = ((long)(gh * WW + gw)) * CC + c4 * 4;
            f4 r = *(const f4*)(ref_in + goff);
            f4 v = *(const f4*)(val_in + goff);
            r_out[0] = pkrtz_u(r.x, r.y);
            r_out[1] = pkrtz_u(r.z, r.w);
            v_out[0] = pkrtz_u(v.x, v.y);
            v_out[1] = pkrtz_u(v.z, v.w);
        }
        *(u2v*)(&s_ref[pix * PIX_STRIDE + c4 * 4]) = r_out;
        *(u2v*)(&s_val[pix * PIX_STRIDE + c4 * 4]) = v_out;
    }

    __syncthreads();

    // ---- Per-pixel compute: one thread per output pixel ----
    const int tx = tid & 15;
    const int ty = tid >> 4;
    const int gh = oy + ty;
    const int gw = ox + tx;

    // Load this pixel's main vector, convert to 16 x half2
    const f4* mp = (const f4*)(main_in + ((long)(gh * WW + gw)) * CC);
    h2 mh[16];
#pragma unroll
    for (int q = 0; q < 8; ++q) {
        f4 m = mp[q];
        mh[2 * q]     = pkrtz(m.x, m.y);
        mh[2 * q + 1] = pkrtz(m.z, m.w);
    }

    // ---- Scores: s[p] = <ref_patch[p], main>, fp32 accum via v_dot2_f32_f16 ----
    float s[K * K];
#pragma unroll
    for (int di = 0; di < K; ++di) {
#pragma unroll
        for (int dj = 0; dj < K; ++dj) {
            const ushort* base = &s_ref[((ty + di) * HALO + (tx + dj)) * PIX_STRIDE];
            float acc = 0.0f;
#pragma unroll
            for (int u = 0; u < 4; ++u) {
                U4H q;
                q.u = *(const u4v*)(base + u * 8);   // 16 B = channels 8u..8u+7
                acc = fdot2f(q.h[0], mh[4 * u + 0], acc);
                acc = fdot2f(q.h[1], mh[4 * u + 1], acc);
                acc = fdot2f(q.h[2], mh[4 * u + 2], acc);
                acc = fdot2f(q.h[3], mh[4 * u + 3], acc);
            }
            s[di * K + dj] = acc;
        }
    }

    // ---- Softmax over the 49 window positions (OOB entries are score 0, val 0) ----
    float m = s[0];
#pragma unroll
    for (int p = 1; p < K * K; ++p) m = fmaxf(m, s[p]);
    float l = 0.0f;
#pragma unroll
    for (int p = 0; p < K * K; ++p) {
        s[p] = __expf(s[p] - m);   // unnormalized weight in (0,1]
        l += s[p];
    }

    // ---- PV: acc[c] += w[p] * val_patch[p][c], fp16 pk_fma, normalize at end ----
    h2 acc[16];
#pragma unroll
    for (int j = 0; j < 16; ++j) acc[j] = h2{(_Float16)0, (_Float16)0};

#pragma unroll
    for (int di = 0; di < K; ++di) {
#pragma unroll
        for (int dj = 0; dj < K; ++dj) {
            const float wf = s[di * K + dj];
            const h2 wh = pkrtz(wf, wf);
            const ushort* base = &s_val[((ty + di) * HALO + (tx + dj)) * PIX_STRIDE];
#pragma unroll
            for (int u = 0; u < 4; ++u) {
                U4H q;
                q.u = *(const u4v*)(base + u * 8);
                acc[4 * u + 0] += wh * q.h[0];
                acc[4 * u + 1] += wh * q.h[1];
                acc[4 * u + 2] += wh * q.h[2];
                acc[4 * u + 3] += wh * q.h[3];
            }
        }
    }

    // ---- Normalize and write fp32 output ----
    const float invl = 1.0f / l;
    float* op = out + ((long)(gh * WW + gw)) * CC;
#pragma unroll
    for (int j = 0; j < 16; ++j) {
        f2 o;
        o.x = (float)acc[j][0] * invl;
        o.y = (float)acc[j][1] * invl;
        *(f2*)(op + 2 * j) = o;
    }
}

extern "C" void kernel_launch(void* const* d_in, const int* in_sizes, int n_in,
                              void* d_out, int out_size, void* d_ws, size_t ws_size,
                              hipStream_t stream) {
    const float* main_in = (const float*)d_in[0];
    const float* ref_in  = (const float*)d_in[1];
    const float* val_in  = (const float*)d_in[2];
    float* o = (float*)d_out;
    dim3 grid(WW / TS, HH / TS);
    local_attn_kernel<<<grid, dim3(256), 0, stream>>>(main_in, ref_in, val_in, o);
}

// Round 3
// 84.082 us; speedup vs baseline: 1.0660x; 1.0660x over previous
//
#include <hip/hip_runtime.h>

#define HH 256
#define WW 256
#define CC 32
#define K 7
#define RAD 3
#define TSX 16
#define TSY 8
#define HX (TSX + K - 1)       /* 22 */
#define HY (TSY + K - 1)       /* 14 */
#define NP (HX * HY)           /* 308 */
#define PIX_STRIDE 40          /* ushorts per pixel: 32 ch + 8 pad = 80 B */
#define NTHREADS 512

typedef _Float16 h2 __attribute__((ext_vector_type(2)));
typedef float f4 __attribute__((ext_vector_type(4)));
typedef unsigned int u32;
typedef u32 u2v __attribute__((ext_vector_type(2)));
typedef u32 u4v __attribute__((ext_vector_type(4)));

union U4H {
    u4v u;
    h2 h[4];
};

static __device__ inline h2 pkrtz(float x, float y) {
    auto t = __builtin_amdgcn_cvt_pkrtz(x, y);
    h2 r;
    __builtin_memcpy(&r, &t, sizeof(r));
    return r;
}

static __device__ inline u32 pkrtz_u(float x, float y) {
    auto t = __builtin_amdgcn_cvt_pkrtz(x, y);
    u32 r;
    __builtin_memcpy(&r, &t, sizeof(r));
    return r;
}

static __device__ inline float fdot2f(h2 a, h2 b, float c) {
#if __has_builtin(__builtin_amdgcn_fdot2)
    return __builtin_amdgcn_fdot2(a, b, c, false);
#else
    return c + (float)a[0] * (float)b[0] + (float)a[1] * (float)b[1];
#endif
}

static __device__ inline h2 shfl_xor_h2(h2 v, int mask) {
    int b;
    __builtin_memcpy(&b, &v, 4);
    b = __shfl_xor(b, mask);
    h2 r;
    __builtin_memcpy(&r, &b, 4);
    return r;
}

__global__ __launch_bounds__(NTHREADS) void local_attn_kernel(
    const float* __restrict__ main_in,
    const float* __restrict__ ref_in,
    const float* __restrict__ val_in,
    float* __restrict__ out)
{
    __shared__ ushort s_ref[NP * PIX_STRIDE];
    __shared__ ushort s_val[NP * PIX_STRIDE];

    const int tid = threadIdx.x;
    const int ox = blockIdx.x * TSX;
    const int oy = blockIdx.y * TSY;

    // ---- Stage ref & ref_value halo tiles into LDS as fp16 (zeros for OOB) ----
    for (int idx = tid; idx < NP * 8; idx += NTHREADS) {
        const int pix = idx >> 3;
        const int c4 = idx & 7;                 // float4 chunk: channels 4*c4..4*c4+3
        const int hy = pix / HX;
        const int wx = pix - hy * HX;
        const int gh = oy + hy - RAD;
        const int gw = ox + wx - RAD;
        u2v r_out = {0u, 0u};
        u2v v_out = {0u, 0u};
        if ((unsigned)gh < (unsigned)HH && (unsigned)gw < (unsigned)WW) {
            const long goff = ((long)(gh * WW + gw)) * CC + c4 * 4;
            f4 r = *(const f4*)(ref_in + goff);
            f4 v = *(const f4*)(val_in + goff);
            r_out[0] = pkrtz_u(r.x, r.y);
            r_out[1] = pkrtz_u(r.z, r.w);
            v_out[0] = pkrtz_u(v.x, v.y);
            v_out[1] = pkrtz_u(v.z, v.w);
        }
        *(u2v*)(&s_ref[pix * PIX_STRIDE + c4 * 4]) = r_out;
        *(u2v*)(&s_val[pix * PIX_STRIDE + c4 * 4]) = v_out;
    }

    __syncthreads();

    // ---- 4 threads per pixel, split over the 49 window positions ----
    const int sub = tid & 3;            // position subset: p = 4*t + sub
    const int px = (tid >> 2) & 15;
    const int py = tid >> 6;            // 0..7
    const int gh = oy + py;
    const int gw = ox + px;

    // Load this pixel's main vector (redundant across 4 subs; L1 broadcast)
    const f4* mp = (const f4*)(main_in + ((long)(gh * WW + gw)) * CC);
    h2 mh[16];
#pragma unroll
    for (int q = 0; q < 8; ++q) {
        f4 m = mp[q];
        mh[2 * q]     = pkrtz(m.x, m.y);
        mh[2 * q + 1] = pkrtz(m.z, m.w);
    }

    // ---- Scores for my 12-13 positions ----
    float w[13];
    float mymax = -1e30f;
#pragma unroll
    for (int t = 0; t < 13; ++t) {
        const int p = 4 * t + sub;
        if (4 * t + 3 < 49 || p < 49) {        // t<12 always; t==12 only sub==0
            const int di = p / 7;
            const int dj = p - di * 7;
            const ushort* base = &s_ref[((py + di) * HX + (px + dj)) * PIX_STRIDE];
            float acc = 0.0f;
#pragma unroll
            for (int u = 0; u < 4; ++u) {
                U4H q;
                q.u = *(const u4v*)(base + u * 8);
                acc = fdot2f(q.h[0], mh[4 * u + 0], acc);
                acc = fdot2f(q.h[1], mh[4 * u + 1], acc);
                acc = fdot2f(q.h[2], mh[4 * u + 2], acc);
                acc = fdot2f(q.h[3], mh[4 * u + 3], acc);
            }
            w[t] = acc;
            mymax = fmaxf(mymax, acc);
        }
    }

    // ---- Global max over the pixel's 4 subs (butterfly over lane^1, lane^2) ----
    float m = mymax;
    m = fmaxf(m, __shfl_xor(m, 1));
    m = fmaxf(m, __shfl_xor(m, 2));

    // ---- exp + partial denominator ----
    float lp = 0.0f;
#pragma unroll
    for (int t = 0; t < 13; ++t) {
        const int p = 4 * t + sub;
        if (4 * t + 3 < 49 || p < 49) {
            w[t] = __expf(w[t] - m);
            lp += w[t];
        }
    }
    float l = lp;
    l += __shfl_xor(l, 1);
    l += __shfl_xor(l, 2);

    // ---- PV over my positions (fp16 accumulate, unnormalized weights) ----
    h2 acc[16];
#pragma unroll
    for (int j = 0; j < 16; ++j) acc[j] = h2{(_Float16)0, (_Float16)0};

#pragma unroll
    for (int t = 0; t < 13; ++t) {
        const int p = 4 * t + sub;
        if (4 * t + 3 < 49 || p < 49) {
            const int di = p / 7;
            const int dj = p - di * 7;
            const float wf = w[t];
            const h2 wh = pkrtz(wf, wf);
            const ushort* base = &s_val[((py + di) * HX + (px + dj)) * PIX_STRIDE];
#pragma unroll
            for (int u = 0; u < 4; ++u) {
                U4H q;
                q.u = *(const u4v*)(base + u * 8);
                acc[4 * u + 0] += wh * q.h[0];
                acc[4 * u + 1] += wh * q.h[1];
                acc[4 * u + 2] += wh * q.h[2];
                acc[4 * u + 3] += wh * q.h[3];
            }
        }
    }

    // ---- Reduce-scatter acc across the 4 subs (all indices compile-time) ----
    // stage 1 (xor 1): fold 16 h2 -> 8 h2
    const bool hi1 = (sub & 1) != 0;
#pragma unroll
    for (int j = 0; j < 8; ++j) {
        h2 mine   = hi1 ? acc[j + 8] : acc[j];
        h2 theirs = shfl_xor_h2(hi1 ? acc[j] : acc[j + 8], 1);
        acc[j] = mine + theirs;
    }
    // stage 2 (xor 2): fold 8 h2 -> 4 h2
    const bool hi2 = (sub & 2) != 0;
#pragma unroll
    for (int j = 0; j < 4; ++j) {
        h2 mine   = hi2 ? acc[j + 4] : acc[j];
        h2 theirs = shfl_xor_h2(hi2 ? acc[j] : acc[j + 4], 2);
        acc[j] = mine + theirs;
    }
    // ownership after reduce-scatter: sub0->ch0-7, sub1->ch16-23, sub2->ch8-15, sub3->ch24-31
    const int chan_base = ((sub & 1) << 4) + ((sub & 2) << 2);

    // ---- Normalize and write my 8 channels ----
    const float invl = 1.0f / l;
    float* op = out + ((long)(gh * WW + gw)) * CC + chan_base;
    f4 o0, o1;
    o0.x = (float)acc[0][0] * invl;
    o0.y = (float)acc[0][1] * invl;
    o0.z = (float)acc[1][0] * invl;
    o0.w = (float)acc[1][1] * invl;
    o1.x = (float)acc[2][0] * invl;
    o1.y = (float)acc[2][1] * invl;
    o1.z = (float)acc[3][0] * invl;
    o1.w = (float)acc[3][1] * invl;
    *(f4*)(op)     = o0;
    *(f4*)(op + 4) = o1;
}

extern "C" void kernel_launch(void* const* d_in, const int* in_sizes, int n_in,
                              void* d_out, int out_size, void* d_ws, size_t ws_size,
                              hipStream_t stream) {
    const float* main_in = (const float*)d_in[0];
    const float* ref_in  = (const float*)d_in[1];
    const float* val_in  = (const float*)d_in[2];
    float* o = (float*)d_out;
    dim3 grid(WW / TSX, HH / TSY);
    local_attn_kernel<<<grid, dim3(NTHREADS), 0, stream>>>(main_in, ref_in, val_in, o);
}